// Round 2
// baseline (752.767 us; speedup 1.0000x reference)
//
#include <hip/hip_runtime.h>
#include <hip/hip_bf16.h>
#include <math.h>

#define VN 4096
#define DIM 128
#define KS 3
#define NH 4
#define HD 32
#define NVIS 8192
#define MAXC 32
#define KTOT (KS*VN)   // 12288

typedef unsigned short u16;
typedef __attribute__((ext_vector_type(8))) short short8;   // 8 bf16 (4 VGPRs)
typedef __attribute__((ext_vector_type(4))) float f32x4;

__device__ __forceinline__ u16 f2b(float f){
  union { float f; unsigned u; } c; c.f = f;
  unsigned u = c.u;
  return (u16)((u + 0x7fffu + ((u >> 16) & 1u)) >> 16);   // RTNE
}
__device__ __forceinline__ float b2f(u16 x){
  union { float f; unsigned u; } c; c.u = ((unsigned)x) << 16; return c.f;
}
#define MFMA16(a,b,c) __builtin_amdgcn_mfma_f32_16x16x32_bf16((a),(b),(c),0,0,0)

// ---------------- logmap0 (f32 in, bf16 out):  Z0 = artanh(||x||)/||x|| * x ----------------
__global__ __launch_bounds__(256) void k_logmap(const float* __restrict__ xh, u16* __restrict__ z0){
  __shared__ float xs[64][132];
  __shared__ float part[4][64];
  __shared__ float sscale[64];
  int t = threadIdx.x;
  int v0 = blockIdx.x * 64;
  #pragma unroll
  for(int i=0;i<8;i++){
    int id = t + 256*i; int e = id*4; int r = e>>7; int c = e&127;
    float4 u = *(const float4*)&xh[(size_t)(v0+r)*DIM + c];
    xs[r][c+0]=u.x; xs[r][c+1]=u.y; xs[r][c+2]=u.z; xs[r][c+3]=u.w;
  }
  __syncthreads();
  int r = t & 63, q = t >> 6;
  float p = 0.f;
  #pragma unroll
  for(int c=0;c<32;c++){ float x = xs[r][q*32+c]; p += x*x; }
  part[q][r] = p;
  __syncthreads();
  if(t < 64){
    float ss = part[0][t]+part[1][t]+part[2][t]+part[3][t];
    float n = sqrtf(ss);
    float nc = fminf(fmaxf(n, 1e-7f), 1.0f - 1e-5f);
    sscale[t] = atanhf(nc) / fmaxf(n, 1e-7f);
  }
  __syncthreads();
  #pragma unroll
  for(int i=0;i<8;i++){
    int id = t + 256*i; int e = id*4; int rr = e>>7; int cc = e&127;
    float s = sscale[rr];
    ushort4 o;
    o.x = f2b(xs[rr][cc+0]*s); o.y = f2b(xs[rr][cc+1]*s);
    o.z = f2b(xs[rr][cc+2]*s); o.w = f2b(xs[rr][cc+3]*s);
    *(ushort4*)&z0[(size_t)(v0+rr)*DIM + cc] = o;
  }
}

// ---------------- shared 128x128-tile GEMM core, K=128 (BK=64 x 2) ----------------
// A[row][kk] (stride lda), B[n][kk] (stride ldb; row n = output col).
// AF32/BF32: source dtype is f32, convert to bf16 while staging into LDS.
// acc[sub][nt]: rows w*32+sub*16+quad*4+reg, cols nt*16+(lane&15)   [C/D layout]
template<bool AF32, bool BF32>
__device__ __forceinline__ void gemm_k128_t(const void* __restrict__ Agv, int lda,
                                            const void* __restrict__ Bgv, int ldb,
                                            u16* As, u16* Bs, f32x4 (&acc)[2][8]){
  int t = threadIdx.x;
  int w=t>>6, lane=t&63, l15=lane&15, quad=lane>>4;
  #pragma unroll
  for(int s=0;s<2;s++)
    #pragma unroll
    for(int n=0;n<8;n++) acc[s][n] = (f32x4){0.f,0.f,0.f,0.f};
  #pragma unroll
  for(int step=0; step<2; step++){
    int kb = step*64;
    __syncthreads();
    #pragma unroll
    for(int i=0;i<4;i++){
      int id = t + 256*i; int row = id>>3, c8 = id&7;
      if(AF32){
        const float* Ag = (const float*)Agv;
        float4 f0 = *(const float4*)&Ag[(size_t)row*lda + kb + c8*8];
        float4 f1 = *(const float4*)&Ag[(size_t)row*lda + kb + c8*8 + 4];
        ushort4 p0 = { f2b(f0.x), f2b(f0.y), f2b(f0.z), f2b(f0.w) };
        ushort4 p1 = { f2b(f1.x), f2b(f1.y), f2b(f1.z), f2b(f1.w) };
        *(ushort4*)&As[row*72 + c8*8]     = p0;
        *(ushort4*)&As[row*72 + c8*8 + 4] = p1;
      } else {
        const u16* Ag = (const u16*)Agv;
        *(uint4*)&As[row*72 + c8*8] = *(const uint4*)&Ag[(size_t)row*lda + kb + c8*8];
      }
      if(BF32){
        const float* Bg = (const float*)Bgv;
        float4 f0 = *(const float4*)&Bg[(size_t)row*ldb + kb + c8*8];
        float4 f1 = *(const float4*)&Bg[(size_t)row*ldb + kb + c8*8 + 4];
        ushort4 p0 = { f2b(f0.x), f2b(f0.y), f2b(f0.z), f2b(f0.w) };
        ushort4 p1 = { f2b(f1.x), f2b(f1.y), f2b(f1.z), f2b(f1.w) };
        *(ushort4*)&Bs[row*72 + c8*8]     = p0;
        *(ushort4*)&Bs[row*72 + c8*8 + 4] = p1;
      } else {
        const u16* Bg = (const u16*)Bgv;
        *(uint4*)&Bs[row*72 + c8*8] = *(const uint4*)&Bg[(size_t)row*ldb + kb + c8*8];
      }
    }
    __syncthreads();
    #pragma unroll
    for(int ks=0; ks<2; ks++){
      short8 a[2], b[8];
      #pragma unroll
      for(int s=0;s<2;s++) a[s] = *(short8*)&As[(w*32+s*16+l15)*72 + (ks*4+quad)*8];
      #pragma unroll
      for(int n=0;n<8;n++)  b[n] = *(short8*)&Bs[(n*16+l15)*72 + (ks*4+quad)*8];
      #pragma unroll
      for(int s=0;s<2;s++)
        #pragma unroll
        for(int n=0;n<8;n++) acc[s][n] = MFMA16(a[s], b[n], acc[s][n]);
    }
  }
}

// ---------------- G[d,k,v] = sum_d' projW[d,k*128+d'] Z0[v,d'], stored gbuf[d][k][v] ----------
__global__ __launch_bounds__(256) void k_gproj(const float* __restrict__ projW, const u16* __restrict__ z0,
                                               u16* __restrict__ gbuf){
  __shared__ u16 As[128*72], Bs[128*72];
  int kb = blockIdx.x >> 5, vt = blockIdx.x & 31;   // grid 96
  f32x4 acc[2][8];
  // A[m=d][kk=d'] = projW[m*384 + kb*128 + kk];  B[n=v][kk=d'] = z0[(vt*128+n)*128+kk]
  gemm_k128_t<true,false>(projW + kb*128, 3*DIM, z0 + (size_t)vt*128*DIM, DIM, As, Bs, acc);
  int t=threadIdx.x, w=t>>6, lane=t&63, l15=lane&15, quad=lane>>4;
  #pragma unroll
  for(int s=0;s<2;s++)
    #pragma unroll
    for(int n=0;n<8;n++)
      #pragma unroll
      for(int rg=0;rg<4;rg++){
        int d = w*32 + s*16 + quad*4 + rg;        // output row = (k,d) with k=kb
        int v = vt*128 + n*16 + l15;
        gbuf[(size_t)(d*KS + kb)*VN + v] = f2b(acc[s][n][rg]);
      }
}

// ---------------- diffusion GEMM: H0[u][d] += sum_{k,v} kernels[k,u,v] G[d,k,v] ----------------
// split-K (16 slices of 768) + f32 atomics. A (kernels) is f32, converted while staging.
__global__ __launch_bounds__(256) void k_diff(const float* __restrict__ kers, const u16* __restrict__ gbuf,
                                              float* __restrict__ h0){
  __shared__ u16 As[128*72], Bs[128*72];
  int t = threadIdx.x;
  int mt = blockIdx.x & 31;     // M tile
  int sl = blockIdx.x >> 5;     // K slice 0..15 (768 each)
  int w=t>>6, lane=t&63, l15=lane&15, quad=lane>>4;
  f32x4 acc[2][8];
  #pragma unroll
  for(int s=0;s<2;s++)
    #pragma unroll
    for(int n=0;n<8;n++) acc[s][n] = (f32x4){0.f,0.f,0.f,0.f};
  int k0 = sl * 768;
  for(int step=0; step<12; step++){
    int kk = k0 + step*64;
    int kout = kk >> 12; int vv = kk & 4095;      // 64-chunks never straddle the v=4096 boundary
    __syncthreads();
    #pragma unroll
    for(int i=0;i<4;i++){
      int id = t + 256*i; int row = id>>3, c8 = id&7;
      const float* ap = &kers[((size_t)kout<<24) + (size_t)(mt*128+row)*VN + vv + c8*8];
      float4 f0 = *(const float4*)ap;
      float4 f1 = *(const float4*)(ap+4);
      ushort4 p0 = { f2b(f0.x), f2b(f0.y), f2b(f0.z), f2b(f0.w) };
      ushort4 p1 = { f2b(f1.x), f2b(f1.y), f2b(f1.z), f2b(f1.w) };
      *(ushort4*)&As[row*72 + c8*8]     = p0;
      *(ushort4*)&As[row*72 + c8*8 + 4] = p1;
      *(uint4*)&Bs[row*72 + c8*8] = *(const uint4*)&gbuf[(size_t)row*KTOT + kk + c8*8];
    }
    __syncthreads();
    #pragma unroll
    for(int ks=0; ks<2; ks++){
      short8 a[2], b[8];
      #pragma unroll
      for(int s=0;s<2;s++) a[s] = *(short8*)&As[(w*32+s*16+l15)*72 + (ks*4+quad)*8];
      #pragma unroll
      for(int n=0;n<8;n++)  b[n] = *(short8*)&Bs[(n*16+l15)*72 + (ks*4+quad)*8];
      #pragma unroll
      for(int s=0;s<2;s++)
        #pragma unroll
        for(int n=0;n<8;n++) acc[s][n] = MFMA16(a[s], b[n], acc[s][n]);
    }
  }
  #pragma unroll
  for(int s=0;s<2;s++)
    #pragma unroll
    for(int n=0;n<8;n++)
      #pragma unroll
      for(int rg=0;rg<4;rg++){
        int row = mt*128 + w*32 + s*16 + quad*4 + rg;
        int col = n*16 + l15;
        atomicAdd(&h0[(size_t)row*DIM + col], acc[s][n][rg]);
      }
}

// ---------------- H0 += proj_b ; also emit bf16 copy ----------------
__global__ __launch_bounds__(256) void k_biascvt(float* __restrict__ h0, const float* __restrict__ pb,
                                                 u16* __restrict__ h0b){
  int idx = blockIdx.x*256 + threadIdx.x;
  float v = h0[idx] + pb[idx & 127];
  h0[idx] = v; h0b[idx] = f2b(v);
}

// ---------------- qkv = x @ Wqkv^T + b (bf16 out) ----------------
__global__ __launch_bounds__(256) void k_qkv(const u16* __restrict__ xb, const float* __restrict__ Wq,
                                             const float* __restrict__ bq, u16* __restrict__ outq){
  __shared__ u16 As[128*72], Bs[128*72];
  int mt = blockIdx.x & 31, ntile = blockIdx.x >> 5;  // grid 96
  f32x4 acc[2][8];
  gemm_k128_t<false,true>(xb + (size_t)mt*128*DIM, DIM, Wq + (size_t)ntile*128*DIM, DIM, As, Bs, acc);
  int t=threadIdx.x, w=t>>6, lane=t&63, l15=lane&15, quad=lane>>4;
  #pragma unroll
  for(int s=0;s<2;s++)
    #pragma unroll
    for(int n=0;n<8;n++)
      #pragma unroll
      for(int rg=0;rg<4;rg++){
        int row = mt*128 + w*32 + s*16 + quad*4 + rg;
        int col = ntile*128 + n*16 + l15;
        outq[(size_t)row*(3*DIM) + col] = f2b(acc[s][n][rg] + bq[col]);
      }
}

// ---------------- flash attention: one block per (head, 64-row q tile) ----------------
__global__ __launch_bounds__(256) void k_attn(const u16* __restrict__ qkv, u16* __restrict__ obuf){
  __shared__ u16 Qs[64*40];
  __shared__ u16 Ksh[128*40];
  __shared__ u16 Vt[32*136];
  __shared__ u16 Ps[4*16*136];
  int t=threadIdx.x; int h = blockIdx.x>>6, qt = blockIdx.x&63;
  int w=t>>6, lane=t&63, l15=lane&15, quad=lane>>4;
  { int r = t>>2, c = t&3;
    *(uint4*)&Qs[r*40 + c*8] = *(const uint4*)&qkv[(size_t)(qt*64+r)*(3*DIM) + h*HD + c*8];
  }
  __syncthreads();
  short8 aq = *(short8*)&Qs[(w*16+l15)*40 + quad*8];
  f32x4 oacc[2]; oacc[0]=(f32x4){0.f,0.f,0.f,0.f}; oacc[1]=(f32x4){0.f,0.f,0.f,0.f};
  float mrun[4], lrun[4];
  #pragma unroll
  for(int rg=0;rg<4;rg++){ mrun[rg] = -INFINITY; lrun[rg] = 0.f; }
  const float sc = 0.17677669529663687f;  // 1/sqrt(32)
  for(int kt=0;kt<32;kt++){
    __syncthreads();
    #pragma unroll
    for(int i=0;i<2;i++){
      int id = t + 256*i; int key = id>>2, c = id&3;
      *(uint4*)&Ksh[key*40 + c*8] =
        *(const uint4*)&qkv[(size_t)(kt*128+key)*(3*DIM) + DIM + h*HD + c*8];
      uint4 vv = *(const uint4*)&qkv[(size_t)(kt*128+key)*(3*DIM) + 2*DIM + h*HD + c*8];
      u16 tmp[8]; *(uint4*)tmp = vv;
      #pragma unroll
      for(int j=0;j<8;j++) Vt[(c*8+j)*136 + key] = tmp[j];
    }
    __syncthreads();
    f32x4 s[8];
    #pragma unroll
    for(int n=0;n<8;n++)
      s[n] = MFMA16(aq, *(short8*)&Ksh[(n*16+l15)*40 + quad*8], ((f32x4){0.f,0.f,0.f,0.f}));
    #pragma unroll
    for(int n=0;n<8;n++)
      #pragma unroll
      for(int rg=0;rg<4;rg++) s[n][rg] *= sc;
    float mx[4];
    #pragma unroll
    for(int rg=0;rg<4;rg++){
      float m = -INFINITY;
      #pragma unroll
      for(int n=0;n<8;n++) m = fmaxf(m, s[n][rg]);
      #pragma unroll
      for(int off=1;off<16;off<<=1) m = fmaxf(m, __shfl_xor(m, off, 64));
      mx[rg] = m;
    }
    float alpha[4], rs[4];
    #pragma unroll
    for(int rg=0;rg<4;rg++){
      float mn = fmaxf(mrun[rg], mx[rg]);
      alpha[rg] = expf(mrun[rg] - mn);
      mrun[rg] = mn; rs[rg] = 0.f;
    }
    #pragma unroll
    for(int n=0;n<8;n++)
      #pragma unroll
      for(int rg=0;rg<4;rg++){
        float p = expf(s[n][rg] - mrun[rg]);
        s[n][rg] = p; rs[rg] += p;
      }
    #pragma unroll
    for(int rg=0;rg<4;rg++){
      #pragma unroll
      for(int off=1;off<16;off<<=1) rs[rg] += __shfl_xor(rs[rg], off, 64);
      lrun[rg] = lrun[rg]*alpha[rg] + rs[rg];
      oacc[0][rg] *= alpha[rg]; oacc[1][rg] *= alpha[rg];
    }
    #pragma unroll
    for(int n=0;n<8;n++)
      #pragma unroll
      for(int rg=0;rg<4;rg++)
        Ps[w*16*136 + (quad*4+rg)*136 + n*16 + l15] = f2b(s[n][rg]);
    __syncthreads();
    #pragma unroll
    for(int kt2=0;kt2<4;kt2++){
      short8 ap = *(short8*)&Ps[w*16*136 + l15*136 + kt2*32 + quad*8];
      #pragma unroll
      for(int n2=0;n2<2;n2++)
        oacc[n2] = MFMA16(ap, *(short8*)&Vt[(n2*16+l15)*136 + kt2*32 + quad*8], oacc[n2]);
    }
  }
  #pragma unroll
  for(int n2=0;n2<2;n2++)
    #pragma unroll
    for(int rg=0;rg<4;rg++){
      int srow = qt*64 + w*16 + quad*4 + rg;
      obuf[(size_t)srow*DIM + h*HD + n2*16 + l15] = f2b(oacc[n2][rg] / lrun[rg]);
    }
}

// ---------------- C = A@W^T + bias + residual, then LayerNorm -> f32 + bf16 ----------------
__global__ __launch_bounds__(256) void k_projln(const u16* __restrict__ Ab, const float* __restrict__ W,
                                                const float* __restrict__ bias, const float* __restrict__ resf,
                                                const float* __restrict__ g, const float* __restrict__ bb,
                                                float* __restrict__ outf, u16* __restrict__ outb){
  __shared__ u16 As[128*72], Bs[128*72];
  int mt = blockIdx.x;   // grid 32
  f32x4 acc[2][8];
  gemm_k128_t<false,true>(Ab + (size_t)mt*128*DIM, DIM, W, DIM, As, Bs, acc);
  int t=threadIdx.x, w=t>>6, lane=t&63, l15=lane&15, quad=lane>>4;
  #pragma unroll
  for(int s=0;s<2;s++)
    #pragma unroll
    for(int n=0;n<8;n++)
      #pragma unroll
      for(int rg=0;rg<4;rg++){
        int row = mt*128 + w*32 + s*16 + quad*4 + rg;
        int col = n*16 + l15;
        acc[s][n][rg] += bias[col] + resf[(size_t)row*DIM + col];
      }
  #pragma unroll
  for(int s=0;s<2;s++)
    #pragma unroll
    for(int rg=0;rg<4;rg++){
      float a=0.f, b=0.f;
      #pragma unroll
      for(int n=0;n<8;n++){ float x = acc[s][n][rg]; a += x; b += x*x; }
      #pragma unroll
      for(int off=1;off<16;off<<=1){ a += __shfl_xor(a, off, 64); b += __shfl_xor(b, off, 64); }
      float mean = a*(1.f/128.f);
      float var  = b*(1.f/128.f) - mean*mean;
      float rstd = rsqrtf(var + 1e-5f);
      #pragma unroll
      for(int n=0;n<8;n++){
        int row = mt*128 + w*32 + s*16 + quad*4 + rg;
        int col = n*16 + l15;
        float y = (acc[s][n][rg] - mean)*rstd*g[col] + bb[col];
        outf[(size_t)row*DIM + col] = y;
        outb[(size_t)row*DIM + col] = f2b(y);
      }
    }
}

// ---------------- ff1 = gelu_tanh(x @ W1^T + b1) -> bf16 ----------------
__global__ __launch_bounds__(256) void k_ff1(const u16* __restrict__ Ab, const float* __restrict__ W,
                                             const float* __restrict__ bias, u16* __restrict__ outb){
  __shared__ u16 As[128*72], Bs[128*72];
  int mt = blockIdx.x;   // grid 32
  f32x4 acc[2][8];
  gemm_k128_t<false,true>(Ab + (size_t)mt*128*DIM, DIM, W, DIM, As, Bs, acc);
  int t=threadIdx.x, w=t>>6, lane=t&63, l15=lane&15, quad=lane>>4;
  #pragma unroll
  for(int s=0;s<2;s++)
    #pragma unroll
    for(int n=0;n<8;n++)
      #pragma unroll
      for(int rg=0;rg<4;rg++){
        int row = mt*128 + w*32 + s*16 + quad*4 + rg;
        int col = n*16 + l15;
        float v = acc[s][n][rg] + bias[col];
        float y = 0.5f*v*(1.f + tanhf(0.7978845608028654f*(v + 0.044715f*v*v*v)));
        outb[(size_t)row*DIM + col] = f2b(y);
      }
}

// ---------------- per-visit masked mean pooling (f32 out) ----------------
__global__ __launch_bounds__(256) void k_pool(const int* __restrict__ visits, const float* __restrict__ xf,
                                              float* __restrict__ out){
  int t = threadIdx.x;
  int vis = blockIdx.x*2 + (t>>7);
  int col = t & 127;
  float s = 0.f; int cnt = 0;
  #pragma unroll
  for(int j=0;j<MAXC;j++){
    int idx = visits[vis*MAXC + j];
    if(idx != 0){ s += xf[(size_t)idx*DIM + col]; cnt++; }
  }
  float r = (cnt > 0) ? s/(float)cnt : 0.f;
  out[(size_t)vis*DIM + col] = r;
}

extern "C" void kernel_launch(void* const* d_in, const int* in_sizes, int n_in,
                              void* d_out, int out_size, void* d_ws, size_t ws_size,
                              hipStream_t stream){
  (void)in_sizes; (void)n_in; (void)out_size; (void)ws_size;
  const int*   visits = (const int*)d_in[0];
  const float* xhyp  = (const float*)d_in[1];
  const float* kers  = (const float*)d_in[2];
  const float* projW = (const float*)d_in[3];
  const float* projb = (const float*)d_in[4];
  const float* Wqkv  = (const float*)d_in[5];
  const float* bqkv  = (const float*)d_in[6];
  const float* Wo    = (const float*)d_in[7];
  const float* bo    = (const float*)d_in[8];
  const float* W1    = (const float*)d_in[9];
  const float* b1    = (const float*)d_in[10];
  const float* W2    = (const float*)d_in[11];
  const float* b2    = (const float*)d_in[12];
  const float* g1    = (const float*)d_in[13];
  const float* be1   = (const float*)d_in[14];
  const float* g2    = (const float*)d_in[15];
  const float* be2   = (const float*)d_in[16];

  char* ws = (char*)d_ws;
  u16*   z0   = (u16*)(ws);                // 1 MB : Z0 bf16 [4096][128]
  u16*   gbuf = (u16*)(ws + (1u<<20));     // 3 MB : G bf16 [128][3][4096]
  float* h0   = (float*)(ws + (4u<<20));   // 2 MB : H0 f32
  u16*   h0b  = (u16*)(ws + (6u<<20));     // 1 MB
  u16*   qkvb = (u16*)(ws + (7u<<20));     // 3 MB
  u16*   obuf = (u16*)(ws + (10u<<20));    // 1 MB
  float* ln1f = (float*)(ws + (11u<<20));  // 2 MB
  u16*   ln1b = (u16*)(ws + (13u<<20));    // 1 MB
  u16*   ffa  = (u16*)(ws + (14u<<20));    // 1 MB
  float* x1f  = (float*)(ws + (15u<<20));  // 2 MB
  u16*   x1b  = (u16*)(ws + (17u<<20));    // 1 MB
  float* x2f  = (float*)(ws + (18u<<20));  // 2 MB
  u16*   x2b  = (u16*)(ws + (20u<<20));    // 1 MB

  k_logmap<<<64,256,0,stream>>>(xhyp, z0);
  k_gproj<<<96,256,0,stream>>>(projW, z0, gbuf);
  hipMemsetAsync(h0, 0, (size_t)VN*DIM*sizeof(float), stream);
  k_diff<<<512,256,0,stream>>>(kers, gbuf, h0);
  k_biascvt<<<2048,256,0,stream>>>(h0, projb, h0b);

  const float* curf = h0; const u16* curb = h0b;
  float* outfs[2] = {x1f, x2f}; u16* outbs[2] = {x1b, x2b};
  for(int l=0;l<2;l++){
    k_qkv<<<96,256,0,stream>>>(curb, Wqkv + (size_t)l*3*DIM*DIM, bqkv + (size_t)l*3*DIM, qkvb);
    k_attn<<<256,256,0,stream>>>(qkvb, obuf);
    k_projln<<<32,256,0,stream>>>(obuf, Wo + (size_t)l*DIM*DIM, bo + (size_t)l*DIM, curf,
                                  g1 + (size_t)l*DIM, be1 + (size_t)l*DIM, ln1f, ln1b);
    k_ff1<<<32,256,0,stream>>>(ln1b, W1 + (size_t)l*DIM*DIM, b1 + (size_t)l*DIM, ffa);
    k_projln<<<32,256,0,stream>>>(ffa, W2 + (size_t)l*DIM*DIM, b2 + (size_t)l*DIM, ln1f,
                                  g2 + (size_t)l*DIM, be2 + (size_t)l*DIM, outfs[l], outbs[l]);
    curf = outfs[l]; curb = outbs[l];
  }
  k_pool<<<4096,256,0,stream>>>(visits, curf, (float*)d_out);
}

// Round 3
// 678.069 us; speedup vs baseline: 1.1102x; 1.1102x over previous
//
#include <hip/hip_runtime.h>
#include <hip/hip_bf16.h>
#include <math.h>

#define VN 4096
#define DIM 128
#define KS 3
#define NH 4
#define HD 32
#define NVIS 8192
#define MAXC 32
#define KTOT (KS*VN)   // 12288

typedef unsigned short u16;
typedef __attribute__((ext_vector_type(8))) short short8;   // 8 bf16 (4 VGPRs)
typedef __attribute__((ext_vector_type(4))) float f32x4;

__device__ __forceinline__ u16 f2b(float f){
  union { float f; unsigned u; } c; c.f = f;
  unsigned u = c.u;
  return (u16)((u + 0x7fffu + ((u >> 16) & 1u)) >> 16);   // RTNE
}
#define MFMA16(a,b,c) __builtin_amdgcn_mfma_f32_16x16x32_bf16((a),(b),(c),0,0,0)

// ---------------- logmap0 (f32 in, bf16 out):  Z0 = artanh(||x||)/||x|| * x ----------------
__global__ __launch_bounds__(256) void k_logmap(const float* __restrict__ xh, u16* __restrict__ z0){
  __shared__ float xs[64][132];
  __shared__ float part[4][64];
  __shared__ float sscale[64];
  int t = threadIdx.x;
  int v0 = blockIdx.x * 64;
  #pragma unroll
  for(int i=0;i<8;i++){
    int id = t + 256*i; int e = id*4; int r = e>>7; int c = e&127;
    float4 u = *(const float4*)&xh[(size_t)(v0+r)*DIM + c];
    xs[r][c+0]=u.x; xs[r][c+1]=u.y; xs[r][c+2]=u.z; xs[r][c+3]=u.w;
  }
  __syncthreads();
  int r = t & 63, q = t >> 6;
  float p = 0.f;
  #pragma unroll
  for(int c=0;c<32;c++){ float x = xs[r][q*32+c]; p += x*x; }
  part[q][r] = p;
  __syncthreads();
  if(t < 64){
    float ss = part[0][t]+part[1][t]+part[2][t]+part[3][t];
    float n = sqrtf(ss);
    float nc = fminf(fmaxf(n, 1e-7f), 1.0f - 1e-5f);
    sscale[t] = atanhf(nc) / fmaxf(n, 1e-7f);
  }
  __syncthreads();
  #pragma unroll
  for(int i=0;i<8;i++){
    int id = t + 256*i; int e = id*4; int rr = e>>7; int cc = e&127;
    float s = sscale[rr];
    ushort4 o;
    o.x = f2b(xs[rr][cc+0]*s); o.y = f2b(xs[rr][cc+1]*s);
    o.z = f2b(xs[rr][cc+2]*s); o.w = f2b(xs[rr][cc+3]*s);
    *(ushort4*)&z0[(size_t)(v0+rr)*DIM + cc] = o;
  }
}

// ---------------- shared 128x128-tile GEMM core, K=128 (BK=64 x 2) ----------------
// A[row][kk] (stride lda), B[n][kk] (stride ldb; row n = output col).
// AF32/BF32: source dtype is f32, convert to bf16 while staging into LDS.
// acc[sub][nt]: rows w*32+sub*16+quad*4+reg, cols nt*16+(lane&15)   [C/D layout]
template<bool AF32, bool BF32>
__device__ __forceinline__ void gemm_k128_t(const void* __restrict__ Agv, int lda,
                                            const void* __restrict__ Bgv, int ldb,
                                            u16* As, u16* Bs, f32x4 (&acc)[2][8]){
  int t = threadIdx.x;
  int w=t>>6, lane=t&63, l15=lane&15, quad=lane>>4;
  #pragma unroll
  for(int s=0;s<2;s++)
    #pragma unroll
    for(int n=0;n<8;n++) acc[s][n] = (f32x4){0.f,0.f,0.f,0.f};
  #pragma unroll
  for(int step=0; step<2; step++){
    int kb = step*64;
    __syncthreads();
    #pragma unroll
    for(int i=0;i<4;i++){
      int id = t + 256*i; int row = id>>3, c8 = id&7;
      if(AF32){
        const float* Ag = (const float*)Agv;
        float4 f0 = *(const float4*)&Ag[(size_t)row*lda + kb + c8*8];
        float4 f1 = *(const float4*)&Ag[(size_t)row*lda + kb + c8*8 + 4];
        ushort4 p0 = { f2b(f0.x), f2b(f0.y), f2b(f0.z), f2b(f0.w) };
        ushort4 p1 = { f2b(f1.x), f2b(f1.y), f2b(f1.z), f2b(f1.w) };
        *(ushort4*)&As[row*72 + c8*8]     = p0;
        *(ushort4*)&As[row*72 + c8*8 + 4] = p1;
      } else {
        const u16* Ag = (const u16*)Agv;
        *(uint4*)&As[row*72 + c8*8] = *(const uint4*)&Ag[(size_t)row*lda + kb + c8*8];
      }
      if(BF32){
        const float* Bg = (const float*)Bgv;
        float4 f0 = *(const float4*)&Bg[(size_t)row*ldb + kb + c8*8];
        float4 f1 = *(const float4*)&Bg[(size_t)row*ldb + kb + c8*8 + 4];
        ushort4 p0 = { f2b(f0.x), f2b(f0.y), f2b(f0.z), f2b(f0.w) };
        ushort4 p1 = { f2b(f1.x), f2b(f1.y), f2b(f1.z), f2b(f1.w) };
        *(ushort4*)&Bs[row*72 + c8*8]     = p0;
        *(ushort4*)&Bs[row*72 + c8*8 + 4] = p1;
      } else {
        const u16* Bg = (const u16*)Bgv;
        *(uint4*)&Bs[row*72 + c8*8] = *(const uint4*)&Bg[(size_t)row*ldb + kb + c8*8];
      }
    }
    __syncthreads();
    #pragma unroll
    for(int ks=0; ks<2; ks++){
      short8 a[2], b[8];
      #pragma unroll
      for(int s=0;s<2;s++) a[s] = *(short8*)&As[(w*32+s*16+l15)*72 + (ks*4+quad)*8];
      #pragma unroll
      for(int n=0;n<8;n++)  b[n] = *(short8*)&Bs[(n*16+l15)*72 + (ks*4+quad)*8];
      #pragma unroll
      for(int s=0;s<2;s++)
        #pragma unroll
        for(int n=0;n<8;n++) acc[s][n] = MFMA16(a[s], b[n], acc[s][n]);
    }
  }
}

// ---------------- G[d,k,v] = sum_d' projW[d,k*128+d'] Z0[v,d'], stored gbuf[d][k][v] ----------
__global__ __launch_bounds__(256) void k_gproj(const float* __restrict__ projW, const u16* __restrict__ z0,
                                               u16* __restrict__ gbuf){
  __shared__ u16 As[128*72], Bs[128*72];
  int kb = blockIdx.x >> 5, vt = blockIdx.x & 31;   // grid 96
  f32x4 acc[2][8];
  gemm_k128_t<true,false>(projW + kb*128, 3*DIM, z0 + (size_t)vt*128*DIM, DIM, As, Bs, acc);
  int t=threadIdx.x, w=t>>6, lane=t&63, l15=lane&15, quad=lane>>4;
  #pragma unroll
  for(int s=0;s<2;s++)
    #pragma unroll
    for(int n=0;n<8;n++)
      #pragma unroll
      for(int rg=0;rg<4;rg++){
        int d = w*32 + s*16 + quad*4 + rg;        // output row = (k,d) with k=kb
        int v = vt*128 + n*16 + l15;
        gbuf[(size_t)(d*KS + kb)*VN + v] = f2b(acc[s][n][rg]);
      }
}

// ---------------- diffusion GEMM: partial[sl][mt] = A_slice @ B_slice (no atomics) ------------
__global__ __launch_bounds__(256) void k_diff(const float* __restrict__ kers, const u16* __restrict__ gbuf,
                                              float* __restrict__ hpart){
  __shared__ u16 As[128*72], Bs[128*72];
  int t = threadIdx.x;
  int mt = blockIdx.x & 31;     // M tile
  int sl = blockIdx.x >> 5;     // K slice 0..15 (768 each)
  int w=t>>6, lane=t&63, l15=lane&15, quad=lane>>4;
  f32x4 acc[2][8];
  #pragma unroll
  for(int s=0;s<2;s++)
    #pragma unroll
    for(int n=0;n<8;n++) acc[s][n] = (f32x4){0.f,0.f,0.f,0.f};
  int k0 = sl * 768;
  for(int step=0; step<12; step++){
    int kk = k0 + step*64;
    int kout = kk >> 12; int vv = kk & 4095;      // 64-chunks never straddle the v=4096 boundary
    __syncthreads();
    #pragma unroll
    for(int i=0;i<4;i++){
      int id = t + 256*i; int row = id>>3, c8 = id&7;
      const float* ap = &kers[((size_t)kout<<24) + (size_t)(mt*128+row)*VN + vv + c8*8];
      float4 f0 = *(const float4*)ap;
      float4 f1 = *(const float4*)(ap+4);
      ushort4 p0 = { f2b(f0.x), f2b(f0.y), f2b(f0.z), f2b(f0.w) };
      ushort4 p1 = { f2b(f1.x), f2b(f1.y), f2b(f1.z), f2b(f1.w) };
      *(ushort4*)&As[row*72 + c8*8]     = p0;
      *(ushort4*)&As[row*72 + c8*8 + 4] = p1;
      *(uint4*)&Bs[row*72 + c8*8] = *(const uint4*)&gbuf[(size_t)row*KTOT + kk + c8*8];
    }
    __syncthreads();
    #pragma unroll
    for(int ks=0; ks<2; ks++){
      short8 a[2], b[8];
      #pragma unroll
      for(int s=0;s<2;s++) a[s] = *(short8*)&As[(w*32+s*16+l15)*72 + (ks*4+quad)*8];
      #pragma unroll
      for(int n=0;n<8;n++)  b[n] = *(short8*)&Bs[(n*16+l15)*72 + (ks*4+quad)*8];
      #pragma unroll
      for(int s=0;s<2;s++)
        #pragma unroll
        for(int n=0;n<8;n++) acc[s][n] = MFMA16(a[s], b[n], acc[s][n]);
    }
  }
  float* dst = hpart + ((size_t)blockIdx.x << 14);   // 128x128 f32 tile per block
  #pragma unroll
  for(int s=0;s<2;s++)
    #pragma unroll
    for(int n=0;n<8;n++)
      #pragma unroll
      for(int rg=0;rg<4;rg++)
        dst[(w*32+s*16+quad*4+rg)*128 + n*16 + l15] = acc[s][n][rg];
}

// ---------------- reduce 16 partials + proj_b -> H0 f32 ----------------
__global__ __launch_bounds__(256) void k_hreduce(const float* __restrict__ hpart, const float* __restrict__ pb,
                                                 float* __restrict__ h0){
  int idx = blockIdx.x*256 + threadIdx.x;   // grid 512 -> 131072 threads, 4 elems each
  #pragma unroll
  for(int j=0;j<4;j++){
    int e = j*131072 + idx;
    float v = pb[e & 127];
    #pragma unroll
    for(int sl=0; sl<16; sl++) v += hpart[((size_t)sl<<19) + e];
    h0[e] = v;
  }
}

// ---------------- qkv = x @ Wqkv^T + b (bf16 out); A dtype templated ----------------
template<bool AF32>
__global__ __launch_bounds__(256) void k_qkv(const void* __restrict__ xb, const float* __restrict__ Wq,
                                             const float* __restrict__ bq, u16* __restrict__ outq){
  __shared__ u16 As[128*72], Bs[128*72];
  int mt = blockIdx.x & 31, ntile = blockIdx.x >> 5;  // grid 96
  f32x4 acc[2][8];
  const void* Ap = AF32 ? (const void*)((const float*)xb + (size_t)mt*128*DIM)
                        : (const void*)((const u16*)xb + (size_t)mt*128*DIM);
  gemm_k128_t<AF32,true>(Ap, DIM, Wq + (size_t)ntile*128*DIM, DIM, As, Bs, acc);
  int t=threadIdx.x, w=t>>6, lane=t&63, l15=lane&15, quad=lane>>4;
  #pragma unroll
  for(int s=0;s<2;s++)
    #pragma unroll
    for(int n=0;n<8;n++)
      #pragma unroll
      for(int rg=0;rg<4;rg++){
        int row = mt*128 + w*32 + s*16 + quad*4 + rg;
        int col = ntile*128 + n*16 + l15;
        outq[(size_t)row*(3*DIM) + col] = f2b(acc[s][n][rg] + bq[col]);
      }
}

// ---------------- flash attention, kt-split x2: one block per (head, qtile64, half) -----------
// emits unnormalized O and per-row (m, l)
__global__ __launch_bounds__(256) void k_attn(const u16* __restrict__ qkv, float* __restrict__ opart,
                                              float* __restrict__ mlpart){
  __shared__ u16 Qs[64*40];
  __shared__ u16 Ksh[128*40];
  __shared__ u16 Vt[32*136];
  __shared__ u16 Ps[4*16*136];
  int t=threadIdx.x;
  int b = blockIdx.x;                       // grid 512
  int h = b>>7, qt = (b>>1)&63, half = b&1;
  int w=t>>6, lane=t&63, l15=lane&15, quad=lane>>4;
  { int r = t>>2, c = t&3;
    *(uint4*)&Qs[r*40 + c*8] = *(const uint4*)&qkv[(size_t)(qt*64+r)*(3*DIM) + h*HD + c*8];
  }
  __syncthreads();
  short8 aq = *(short8*)&Qs[(w*16+l15)*40 + quad*8];
  f32x4 oacc[2]; oacc[0]=(f32x4){0.f,0.f,0.f,0.f}; oacc[1]=(f32x4){0.f,0.f,0.f,0.f};
  float mrun[4], lrun[4];
  #pragma unroll
  for(int rg=0;rg<4;rg++){ mrun[rg] = -INFINITY; lrun[rg] = 0.f; }
  const float sc = 0.17677669529663687f;  // 1/sqrt(32)
  for(int kti=0;kti<16;kti++){
    int kt = half*16 + kti;
    __syncthreads();
    #pragma unroll
    for(int i=0;i<2;i++){
      int id = t + 256*i; int key = id>>2, c = id&3;
      *(uint4*)&Ksh[key*40 + c*8] =
        *(const uint4*)&qkv[(size_t)(kt*128+key)*(3*DIM) + DIM + h*HD + c*8];
      uint4 vv = *(const uint4*)&qkv[(size_t)(kt*128+key)*(3*DIM) + 2*DIM + h*HD + c*8];
      u16 tmp[8]; *(uint4*)tmp = vv;
      #pragma unroll
      for(int j=0;j<8;j++) Vt[(c*8+j)*136 + key] = tmp[j];
    }
    __syncthreads();
    f32x4 s[8];
    #pragma unroll
    for(int n=0;n<8;n++)
      s[n] = MFMA16(aq, *(short8*)&Ksh[(n*16+l15)*40 + quad*8], ((f32x4){0.f,0.f,0.f,0.f}));
    #pragma unroll
    for(int n=0;n<8;n++)
      #pragma unroll
      for(int rg=0;rg<4;rg++) s[n][rg] *= sc;
    float mx[4];
    #pragma unroll
    for(int rg=0;rg<4;rg++){
      float m = -INFINITY;
      #pragma unroll
      for(int n=0;n<8;n++) m = fmaxf(m, s[n][rg]);
      #pragma unroll
      for(int off=1;off<16;off<<=1) m = fmaxf(m, __shfl_xor(m, off, 64));
      mx[rg] = m;
    }
    float alpha[4], rs[4];
    #pragma unroll
    for(int rg=0;rg<4;rg++){
      float mn = fmaxf(mrun[rg], mx[rg]);
      alpha[rg] = expf(mrun[rg] - mn);
      mrun[rg] = mn; rs[rg] = 0.f;
    }
    #pragma unroll
    for(int n=0;n<8;n++)
      #pragma unroll
      for(int rg=0;rg<4;rg++){
        float p = expf(s[n][rg] - mrun[rg]);
        s[n][rg] = p; rs[rg] += p;
      }
    #pragma unroll
    for(int rg=0;rg<4;rg++){
      #pragma unroll
      for(int off=1;off<16;off<<=1) rs[rg] += __shfl_xor(rs[rg], off, 64);
      lrun[rg] = lrun[rg]*alpha[rg] + rs[rg];
      oacc[0][rg] *= alpha[rg]; oacc[1][rg] *= alpha[rg];
    }
    #pragma unroll
    for(int n=0;n<8;n++)
      #pragma unroll
      for(int rg=0;rg<4;rg++)
        Ps[w*16*136 + (quad*4+rg)*136 + n*16 + l15] = f2b(s[n][rg]);
    __syncthreads();
    #pragma unroll
    for(int kt2=0;kt2<4;kt2++){
      short8 ap = *(short8*)&Ps[w*16*136 + l15*136 + kt2*32 + quad*8];
      #pragma unroll
      for(int n2=0;n2<2;n2++)
        oacc[n2] = MFMA16(ap, *(short8*)&Vt[(n2*16+l15)*136 + kt2*32 + quad*8], oacc[n2]);
    }
  }
  // write unnormalized partials
  float* op = opart + ((size_t)b << 11);          // 64 x 32 f32
  #pragma unroll
  for(int n2=0;n2<2;n2++)
    #pragma unroll
    for(int rg=0;rg<4;rg++)
      op[(w*16+quad*4+rg)*32 + n2*16 + l15] = oacc[n2][rg];
  if(l15 == 0){
    float* ml = mlpart + ((size_t)b << 7);        // [2][64]
    #pragma unroll
    for(int rg=0;rg<4;rg++){
      int r = w*16 + quad*4 + rg;
      ml[r] = mrun[rg]; ml[64 + r] = lrun[rg];
    }
  }
}

// ---------------- combine the two kt-halves -> obuf bf16 ----------------
__global__ __launch_bounds__(256) void k_attncomb(const float* __restrict__ opart, const float* __restrict__ mlpart,
                                                  u16* __restrict__ obuf){
  int hq = blockIdx.x;            // grid 256: h*64 + qt
  int h = hq>>6, qt = hq&63;
  int t = threadIdx.x;
  int r = t>>2, c8 = (t&3)*8;
  const float* o0 = opart + ((size_t)(hq*2+0) << 11);
  const float* o1 = opart + ((size_t)(hq*2+1) << 11);
  const float* ml0 = mlpart + ((size_t)(hq*2+0) << 7);
  const float* ml1 = mlpart + ((size_t)(hq*2+1) << 7);
  float m0 = ml0[r], l0 = ml0[64+r], m1 = ml1[r], l1 = ml1[64+r];
  float m = fmaxf(m0, m1);
  float w0 = expf(m0 - m), w1 = expf(m1 - m);
  float inv = 1.f / (l0*w0 + l1*w1);
  #pragma unroll
  for(int j=0;j<8;j++){
    int c = c8 + j;
    float v = (o0[r*32 + c]*w0 + o1[r*32 + c]*w1) * inv;
    obuf[(size_t)(qt*64 + r)*DIM + h*HD + c] = f2b(v);
  }
}

// ---------------- C = A@W^T + bias + residual, then LayerNorm -> f32 + bf16 ----------------
__global__ __launch_bounds__(256) void k_projln(const u16* __restrict__ Ab, const float* __restrict__ W,
                                                const float* __restrict__ bias, const float* __restrict__ resf,
                                                const float* __restrict__ g, const float* __restrict__ bb,
                                                float* __restrict__ outf, u16* __restrict__ outb){
  __shared__ u16 As[128*72], Bs[128*72];
  int mt = blockIdx.x;   // grid 32
  f32x4 acc[2][8];
  gemm_k128_t<false,true>(Ab + (size_t)mt*128*DIM, DIM, W, DIM, As, Bs, acc);
  int t=threadIdx.x, w=t>>6, lane=t&63, l15=lane&15, quad=lane>>4;
  #pragma unroll
  for(int s=0;s<2;s++)
    #pragma unroll
    for(int n=0;n<8;n++)
      #pragma unroll
      for(int rg=0;rg<4;rg++){
        int row = mt*128 + w*32 + s*16 + quad*4 + rg;
        int col = n*16 + l15;
        acc[s][n][rg] += bias[col] + resf[(size_t)row*DIM + col];
      }
  #pragma unroll
  for(int s=0;s<2;s++)
    #pragma unroll
    for(int rg=0;rg<4;rg++){
      float a=0.f, b=0.f;
      #pragma unroll
      for(int n=0;n<8;n++){ float x = acc[s][n][rg]; a += x; b += x*x; }
      #pragma unroll
      for(int off=1;off<16;off<<=1){ a += __shfl_xor(a, off, 64); b += __shfl_xor(b, off, 64); }
      float mean = a*(1.f/128.f);
      float var  = b*(1.f/128.f) - mean*mean;
      float rstd = rsqrtf(var + 1e-5f);
      #pragma unroll
      for(int n=0;n<8;n++){
        int row = mt*128 + w*32 + s*16 + quad*4 + rg;
        int col = n*16 + l15;
        float y = (acc[s][n][rg] - mean)*rstd*g[col] + bb[col];
        outf[(size_t)row*DIM + col] = y;
        outb[(size_t)row*DIM + col] = f2b(y);
      }
    }
}

// ---------------- ff1 = gelu_tanh(x @ W1^T + b1) -> bf16 ----------------
__global__ __launch_bounds__(256) void k_ff1(const u16* __restrict__ Ab, const float* __restrict__ W,
                                             const float* __restrict__ bias, u16* __restrict__ outb){
  __shared__ u16 As[128*72], Bs[128*72];
  int mt = blockIdx.x;   // grid 32
  f32x4 acc[2][8];
  gemm_k128_t<false,true>(Ab + (size_t)mt*128*DIM, DIM, W, DIM, As, Bs, acc);
  int t=threadIdx.x, w=t>>6, lane=t&63, l15=lane&15, quad=lane>>4;
  #pragma unroll
  for(int s=0;s<2;s++)
    #pragma unroll
    for(int n=0;n<8;n++)
      #pragma unroll
      for(int rg=0;rg<4;rg++){
        int row = mt*128 + w*32 + s*16 + quad*4 + rg;
        int col = n*16 + l15;
        float v = acc[s][n][rg] + bias[col];
        float y = 0.5f*v*(1.f + tanhf(0.7978845608028654f*(v + 0.044715f*v*v*v)));
        outb[(size_t)row*DIM + col] = f2b(y);
      }
}

// ---------------- per-visit masked mean pooling (f32 out) ----------------
__global__ __launch_bounds__(256) void k_pool(const int* __restrict__ visits, const float* __restrict__ xf,
                                              float* __restrict__ out){
  int t = threadIdx.x;
  int vis = blockIdx.x*2 + (t>>7);
  int col = t & 127;
  float s = 0.f; int cnt = 0;
  #pragma unroll
  for(int j=0;j<MAXC;j++){
    int idx = visits[vis*MAXC + j];
    if(idx != 0){ s += xf[(size_t)idx*DIM + col]; cnt++; }
  }
  float r = (cnt > 0) ? s/(float)cnt : 0.f;
  out[(size_t)vis*DIM + col] = r;
}

extern "C" void kernel_launch(void* const* d_in, const int* in_sizes, int n_in,
                              void* d_out, int out_size, void* d_ws, size_t ws_size,
                              hipStream_t stream){
  (void)in_sizes; (void)n_in; (void)out_size; (void)ws_size;
  const int*   visits = (const int*)d_in[0];
  const float* xhyp  = (const float*)d_in[1];
  const float* kers  = (const float*)d_in[2];
  const float* projW = (const float*)d_in[3];
  const float* projb = (const float*)d_in[4];
  const float* Wqkv  = (const float*)d_in[5];
  const float* bqkv  = (const float*)d_in[6];
  const float* Wo    = (const float*)d_in[7];
  const float* bo    = (const float*)d_in[8];
  const float* W1    = (const float*)d_in[9];
  const float* b1    = (const float*)d_in[10];
  const float* W2    = (const float*)d_in[11];
  const float* b2    = (const float*)d_in[12];
  const float* g1    = (const float*)d_in[13];
  const float* be1   = (const float*)d_in[14];
  const float* g2    = (const float*)d_in[15];
  const float* be2   = (const float*)d_in[16];

  char* ws = (char*)d_ws;
  u16*   z0    = (u16*)(ws);                // 1 MB : Z0 bf16 [4096][128]
  u16*   gbuf  = (u16*)(ws + (1u<<20));     // 3 MB : G bf16 [128][3][4096]
  float* h0    = (float*)(ws + (4u<<20));   // 2 MB : H0 f32
  u16*   qkvb  = (u16*)(ws + (7u<<20));     // 3 MB
  u16*   obuf  = (u16*)(ws + (10u<<20));    // 1 MB
  float* ln1f  = (float*)(ws + (11u<<20));  // 2 MB
  u16*   ln1b  = (u16*)(ws + (13u<<20));    // 1 MB
  u16*   ffa   = (u16*)(ws + (14u<<20));    // 1 MB
  float* x1f   = (float*)(ws + (15u<<20));  // 2 MB
  u16*   x1b   = (u16*)(ws + (17u<<20));    // 1 MB
  float* x2f   = (float*)(ws + (18u<<20));  // 2 MB
  u16*   x2b   = (u16*)(ws + (20u<<20));    // 1 MB
  float* hpart = (float*)(ws + (21u<<20));  // 32 MB : 512 x (128x128) f32 partials
  float* opart = (float*)(ws + (53u<<20));  // 4 MB  : 512 x (64x32) f32
  float* mlprt = (float*)(ws + (57u<<20));  // 256 KB: 512 x [2][64] f32

  k_logmap<<<64,256,0,stream>>>(xhyp, z0);
  k_gproj<<<96,256,0,stream>>>(projW, z0, gbuf);
  k_diff<<<512,256,0,stream>>>(kers, gbuf, hpart);
  k_hreduce<<<512,256,0,stream>>>(hpart, projb, h0);

  const void* curA = (const void*)h0; bool af32 = true;
  const float* curf = h0;
  float* outfs[2] = {x1f, x2f}; u16* outbs[2] = {x1b, x2b};
  for(int l=0;l<2;l++){
    if(af32) k_qkv<true ><<<96,256,0,stream>>>(curA, Wqkv + (size_t)l*3*DIM*DIM, bqkv + (size_t)l*3*DIM, qkvb);
    else     k_qkv<false><<<96,256,0,stream>>>(curA, Wqkv + (size_t)l*3*DIM*DIM, bqkv + (size_t)l*3*DIM, qkvb);
    k_attn<<<512,256,0,stream>>>(qkvb, opart, mlprt);
    k_attncomb<<<256,256,0,stream>>>(opart, mlprt, obuf);
    k_projln<<<32,256,0,stream>>>(obuf, Wo + (size_t)l*DIM*DIM, bo + (size_t)l*DIM, curf,
                                  g1 + (size_t)l*DIM, be1 + (size_t)l*DIM, ln1f, ln1b);
    k_ff1<<<32,256,0,stream>>>(ln1b, W1 + (size_t)l*DIM*DIM, b1 + (size_t)l*DIM, ffa);
    k_projln<<<32,256,0,stream>>>(ffa, W2 + (size_t)l*DIM*DIM, b2 + (size_t)l*DIM, ln1f,
                                  g2 + (size_t)l*DIM, be2 + (size_t)l*DIM, outfs[l], outbs[l]);
    curA = (const void*)outbs[l]; af32 = false; curf = outfs[l];
  }
  k_pool<<<4096,256,0,stream>>>(visits, curf, (float*)d_out);
}

// Round 4
// 589.531 us; speedup vs baseline: 1.2769x; 1.1502x over previous
//
#include <hip/hip_runtime.h>
#include <hip/hip_bf16.h>
#include <math.h>

#define VN 4096
#define DIM 128
#define KS 3
#define NH 4
#define HD 32
#define NVIS 8192
#define MAXC 32
#define KTOT (KS*VN)   // 12288

typedef unsigned short u16;
typedef __attribute__((ext_vector_type(8))) short short8;   // 8 bf16 (4 VGPRs)
typedef __attribute__((ext_vector_type(4))) float f32x4;

__device__ __forceinline__ u16 f2b(float f){
  union { float f; unsigned u; } c; c.f = f;
  unsigned u = c.u;
  return (u16)((u + 0x7fffu + ((u >> 16) & 1u)) >> 16);   // RTNE
}
__device__ __forceinline__ float b2f(u16 x){
  union { float f; unsigned u; } c; c.u = ((unsigned)x) << 16; return c.f;
}
#define MFMA16(a,b,c) __builtin_amdgcn_mfma_f32_16x16x32_bf16((a),(b),(c),0,0,0)

// ---------------- logmap0 (f32 in, bf16 out):  Z0 = artanh(||x||)/||x|| * x ----------------
__global__ __launch_bounds__(256) void k_logmap(const float* __restrict__ xh, u16* __restrict__ z0){
  __shared__ float xs[64][132];
  __shared__ float part[4][64];
  __shared__ float sscale[64];
  int t = threadIdx.x;
  int v0 = blockIdx.x * 64;
  #pragma unroll
  for(int i=0;i<8;i++){
    int id = t + 256*i; int e = id*4; int r = e>>7; int c = e&127;
    float4 u = *(const float4*)&xh[(size_t)(v0+r)*DIM + c];
    xs[r][c+0]=u.x; xs[r][c+1]=u.y; xs[r][c+2]=u.z; xs[r][c+3]=u.w;
  }
  __syncthreads();
  int r = t & 63, q = t >> 6;
  float p = 0.f;
  #pragma unroll
  for(int c=0;c<32;c++){ float x = xs[r][q*32+c]; p += x*x; }
  part[q][r] = p;
  __syncthreads();
  if(t < 64){
    float ss = part[0][t]+part[1][t]+part[2][t]+part[3][t];
    float n = sqrtf(ss);
    float nc = fminf(fmaxf(n, 1e-7f), 1.0f - 1e-5f);
    sscale[t] = atanhf(nc) / fmaxf(n, 1e-7f);
  }
  __syncthreads();
  #pragma unroll
  for(int i=0;i<8;i++){
    int id = t + 256*i; int e = id*4; int rr = e>>7; int cc = e&127;
    float s = sscale[rr];
    ushort4 o;
    o.x = f2b(xs[rr][cc+0]*s); o.y = f2b(xs[rr][cc+1]*s);
    o.z = f2b(xs[rr][cc+2]*s); o.w = f2b(xs[rr][cc+3]*s);
    *(ushort4*)&z0[(size_t)(v0+rr)*DIM + cc] = o;
  }
}

// ---------------- shared 128x128-tile GEMM core, K=128 (BK=64 x 2) ----------------
template<bool AF32, bool BF32>
__device__ __forceinline__ void gemm_k128_t(const void* __restrict__ Agv, int lda,
                                            const void* __restrict__ Bgv, int ldb,
                                            u16* As, u16* Bs, f32x4 (&acc)[2][8]){
  int t = threadIdx.x;
  int w=t>>6, lane=t&63, l15=lane&15, quad=lane>>4;
  #pragma unroll
  for(int s=0;s<2;s++)
    #pragma unroll
    for(int n=0;n<8;n++) acc[s][n] = (f32x4){0.f,0.f,0.f,0.f};
  #pragma unroll
  for(int step=0; step<2; step++){
    int kb = step*64;
    __syncthreads();
    #pragma unroll
    for(int i=0;i<4;i++){
      int id = t + 256*i; int row = id>>3, c8 = id&7;
      if(AF32){
        const float* Ag = (const float*)Agv;
        float4 f0 = *(const float4*)&Ag[(size_t)row*lda + kb + c8*8];
        float4 f1 = *(const float4*)&Ag[(size_t)row*lda + kb + c8*8 + 4];
        ushort4 p0 = { f2b(f0.x), f2b(f0.y), f2b(f0.z), f2b(f0.w) };
        ushort4 p1 = { f2b(f1.x), f2b(f1.y), f2b(f1.z), f2b(f1.w) };
        *(ushort4*)&As[row*72 + c8*8]     = p0;
        *(ushort4*)&As[row*72 + c8*8 + 4] = p1;
      } else {
        const u16* Ag = (const u16*)Agv;
        *(uint4*)&As[row*72 + c8*8] = *(const uint4*)&Ag[(size_t)row*lda + kb + c8*8];
      }
      if(BF32){
        const float* Bg = (const float*)Bgv;
        float4 f0 = *(const float4*)&Bg[(size_t)row*ldb + kb + c8*8];
        float4 f1 = *(const float4*)&Bg[(size_t)row*ldb + kb + c8*8 + 4];
        ushort4 p0 = { f2b(f0.x), f2b(f0.y), f2b(f0.z), f2b(f0.w) };
        ushort4 p1 = { f2b(f1.x), f2b(f1.y), f2b(f1.z), f2b(f1.w) };
        *(ushort4*)&Bs[row*72 + c8*8]     = p0;
        *(ushort4*)&Bs[row*72 + c8*8 + 4] = p1;
      } else {
        const u16* Bg = (const u16*)Bgv;
        *(uint4*)&Bs[row*72 + c8*8] = *(const uint4*)&Bg[(size_t)row*ldb + kb + c8*8];
      }
    }
    __syncthreads();
    #pragma unroll
    for(int ks=0; ks<2; ks++){
      short8 a[2], b[8];
      #pragma unroll
      for(int s=0;s<2;s++) a[s] = *(short8*)&As[(w*32+s*16+l15)*72 + (ks*4+quad)*8];
      #pragma unroll
      for(int n=0;n<8;n++)  b[n] = *(short8*)&Bs[(n*16+l15)*72 + (ks*4+quad)*8];
      #pragma unroll
      for(int s=0;s<2;s++)
        #pragma unroll
        for(int n=0;n<8;n++) acc[s][n] = MFMA16(a[s], b[n], acc[s][n]);
    }
  }
}

// ---------------- G[d,k,v] = sum_d' projW[d,k*128+d'] Z0[v,d'], stored gbuf[d][k][v] ----------
__global__ __launch_bounds__(256) void k_gproj(const float* __restrict__ projW, const u16* __restrict__ z0,
                                               u16* __restrict__ gbuf){
  __shared__ u16 As[128*72], Bs[128*72];
  int kb = blockIdx.x >> 5, vt = blockIdx.x & 31;   // grid 96
  f32x4 acc[2][8];
  gemm_k128_t<true,false>(projW + kb*128, 3*DIM, z0 + (size_t)vt*128*DIM, DIM, As, Bs, acc);
  int t=threadIdx.x, w=t>>6, lane=t&63, l15=lane&15, quad=lane>>4;
  #pragma unroll
  for(int s=0;s<2;s++)
    #pragma unroll
    for(int n=0;n<8;n++)
      #pragma unroll
      for(int rg=0;rg<4;rg++){
        int d = w*32 + s*16 + quad*4 + rg;        // output row = (k,d) with k=kb
        int v = vt*128 + n*16 + l15;
        gbuf[(size_t)(d*KS + kb)*VN + v] = f2b(acc[s][n][rg]);
      }
}

// ---------------- diffusion GEMM: bf16 partial tiles, no atomics ------------
__global__ __launch_bounds__(256) void k_diff(const float* __restrict__ kers, const u16* __restrict__ gbuf,
                                              u16* __restrict__ hpart){
  __shared__ u16 As[128*72], Bs[128*72];
  int t = threadIdx.x;
  int mt = blockIdx.x & 31;     // M tile
  int sl = blockIdx.x >> 5;     // K slice 0..15 (768 each)
  int w=t>>6, lane=t&63, l15=lane&15, quad=lane>>4;
  f32x4 acc[2][8];
  #pragma unroll
  for(int s=0;s<2;s++)
    #pragma unroll
    for(int n=0;n<8;n++) acc[s][n] = (f32x4){0.f,0.f,0.f,0.f};
  int k0 = sl * 768;
  for(int step=0; step<12; step++){
    int kk = k0 + step*64;
    int kout = kk >> 12; int vv = kk & 4095;      // 64-chunks never straddle the v=4096 boundary
    __syncthreads();
    #pragma unroll
    for(int i=0;i<4;i++){
      int id = t + 256*i; int row = id>>3, c8 = id&7;
      const float* ap = &kers[((size_t)kout<<24) + (size_t)(mt*128+row)*VN + vv + c8*8];
      float4 f0 = *(const float4*)ap;
      float4 f1 = *(const float4*)(ap+4);
      ushort4 p0 = { f2b(f0.x), f2b(f0.y), f2b(f0.z), f2b(f0.w) };
      ushort4 p1 = { f2b(f1.x), f2b(f1.y), f2b(f1.z), f2b(f1.w) };
      *(ushort4*)&As[row*72 + c8*8]     = p0;
      *(ushort4*)&As[row*72 + c8*8 + 4] = p1;
      *(uint4*)&Bs[row*72 + c8*8] = *(const uint4*)&gbuf[(size_t)row*KTOT + kk + c8*8];
    }
    __syncthreads();
    #pragma unroll
    for(int ks=0; ks<2; ks++){
      short8 a[2], b[8];
      #pragma unroll
      for(int s=0;s<2;s++) a[s] = *(short8*)&As[(w*32+s*16+l15)*72 + (ks*4+quad)*8];
      #pragma unroll
      for(int n=0;n<8;n++)  b[n] = *(short8*)&Bs[(n*16+l15)*72 + (ks*4+quad)*8];
      #pragma unroll
      for(int s=0;s<2;s++)
        #pragma unroll
        for(int n=0;n<8;n++) acc[s][n] = MFMA16(a[s], b[n], acc[s][n]);
    }
  }
  u16* dst = hpart + ((size_t)blockIdx.x << 14);   // 128x128 bf16 tile per block
  #pragma unroll
  for(int s=0;s<2;s++)
    #pragma unroll
    for(int n=0;n<8;n++)
      #pragma unroll
      for(int rg=0;rg<4;rg++)
        dst[(w*32+s*16+quad*4+rg)*128 + n*16 + l15] = f2b(acc[s][n][rg]);
}

// ---------------- reduce 16 bf16 partials + proj_b -> H0 f32 ----------------
__global__ __launch_bounds__(256) void k_hreduce(const u16* __restrict__ hpart, const float* __restrict__ pb,
                                                 float* __restrict__ h0){
  int idx = blockIdx.x*256 + threadIdx.x;   // grid 512 -> 131072 threads, 4 elems each
  #pragma unroll
  for(int j=0;j<4;j++){
    int e = j*131072 + idx;
    float v = pb[e & 127];
    #pragma unroll
    for(int sl=0; sl<16; sl++) v += b2f(hpart[((size_t)sl<<19) + e]);
    h0[e] = v;
  }
}

// ---------------- qkv = x @ Wqkv^T + b (bf16 out); A dtype templated ----------------
template<bool AF32>
__global__ __launch_bounds__(256) void k_qkv(const void* __restrict__ xb, const float* __restrict__ Wq,
                                             const float* __restrict__ bq, u16* __restrict__ outq){
  __shared__ u16 As[128*72], Bs[128*72];
  int mt = blockIdx.x & 31, ntile = blockIdx.x >> 5;  // grid 96
  f32x4 acc[2][8];
  const void* Ap = AF32 ? (const void*)((const float*)xb + (size_t)mt*128*DIM)
                        : (const void*)((const u16*)xb + (size_t)mt*128*DIM);
  gemm_k128_t<AF32,true>(Ap, DIM, Wq + (size_t)ntile*128*DIM, DIM, As, Bs, acc);
  int t=threadIdx.x, w=t>>6, lane=t&63, l15=lane&15, quad=lane>>4;
  #pragma unroll
  for(int s=0;s<2;s++)
    #pragma unroll
    for(int n=0;n<8;n++)
      #pragma unroll
      for(int rg=0;rg<4;rg++){
        int row = mt*128 + w*32 + s*16 + quad*4 + rg;
        int col = ntile*128 + n*16 + l15;
        outq[(size_t)row*(3*DIM) + col] = f2b(acc[s][n][rg] + bq[col]);
      }
}

// ---------------- flash attention, kt-split x2, software-pipelined K/V ----------------
// 1 barrier/iter: global->VGPR loads issued before compute, VGPR->LDS after.
// emits unnormalized O and per-row (m_scaled, l)
__global__ __launch_bounds__(256) void k_attn(const u16* __restrict__ qkv, float* __restrict__ opart,
                                              float* __restrict__ mlpart){
  __shared__ u16 Qs[64*40];
  __shared__ u16 Ksh[2][128*40];
  __shared__ u16 Vt[2][32*136];
  __shared__ u16 Ps[4*16*136];
  int t=threadIdx.x;
  int b = blockIdx.x;                       // grid 512
  int h = b>>7, qt = (b>>1)&63, half = b&1;
  int w=t>>6, lane=t&63, l15=lane&15, quad=lane>>4;
  { int r = t>>2, c = t&3;
    *(uint4*)&Qs[r*40 + c*8] = *(const uint4*)&qkv[(size_t)(qt*64+r)*(3*DIM) + h*HD + c*8];
  }
  int skey = t>>2, sc4 = t&3;               // staging coords (2 iters: skey, skey+64)
  uint4 kreg[2], vreg[2];
  #pragma unroll
  for(int i=0;i<2;i++){
    int key = skey + 64*i;
    kreg[i] = *(const uint4*)&qkv[(size_t)((size_t)(half*16)*128+key)*(3*DIM) + DIM + h*HD + sc4*8];
    vreg[i] = *(const uint4*)&qkv[(size_t)((size_t)(half*16)*128+key)*(3*DIM) + 2*DIM + h*HD + sc4*8];
  }
  #pragma unroll
  for(int i=0;i<2;i++){
    int key = skey + 64*i;
    *(uint4*)&Ksh[0][key*40 + sc4*8] = kreg[i];
    u16 tmp[8]; *(uint4*)tmp = vreg[i];
    #pragma unroll
    for(int j=0;j<8;j++) Vt[0][(sc4*8+j)*136 + key] = tmp[j];
  }
  __syncthreads();
  short8 aq = *(short8*)&Qs[(w*16+l15)*40 + quad*8];
  f32x4 oacc[2]; oacc[0]=(f32x4){0.f,0.f,0.f,0.f}; oacc[1]=(f32x4){0.f,0.f,0.f,0.f};
  float mrun[4], lrun[4];
  #pragma unroll
  for(int rg=0;rg<4;rg++){ mrun[rg] = -INFINITY; lrun[rg] = 0.f; }
  const float sc = 0.17677669529663687f;  // 1/sqrt(32)
  for(int kti=0;kti<16;kti++){
    int cur = kti&1;
    if(kti<15){                             // issue next K/V global loads (no wait yet)
      int kt = half*16 + kti + 1;
      #pragma unroll
      for(int i=0;i<2;i++){
        int key = skey + 64*i;
        kreg[i] = *(const uint4*)&qkv[(size_t)(kt*128+key)*(3*DIM) + DIM + h*HD + sc4*8];
        vreg[i] = *(const uint4*)&qkv[(size_t)(kt*128+key)*(3*DIM) + 2*DIM + h*HD + sc4*8];
      }
    }
    f32x4 s[8];
    #pragma unroll
    for(int n=0;n<8;n++)
      s[n] = MFMA16(aq, *(short8*)&Ksh[cur][(n*16+l15)*40 + quad*8], ((f32x4){0.f,0.f,0.f,0.f}));
    float mx[4];
    #pragma unroll
    for(int rg=0;rg<4;rg++){
      float m = -INFINITY;
      #pragma unroll
      for(int n=0;n<8;n++) m = fmaxf(m, s[n][rg]);
      #pragma unroll
      for(int off=1;off<16;off<<=1) m = fmaxf(m, __shfl_xor(m, off, 64));
      mx[rg] = m;
    }
    float alpha[4], rs[4];
    #pragma unroll
    for(int rg=0;rg<4;rg++){
      float mn = fmaxf(mrun[rg], mx[rg]);
      alpha[rg] = __expf(sc*(mrun[rg] - mn));   // raw-domain m, scale folded into exp
      mrun[rg] = mn; rs[rg] = 0.f;
    }
    #pragma unroll
    for(int n=0;n<8;n++)
      #pragma unroll
      for(int rg=0;rg<4;rg++){
        float p = __expf(sc*(s[n][rg] - mrun[rg]));
        s[n][rg] = p; rs[rg] += p;
      }
    #pragma unroll
    for(int rg=0;rg<4;rg++){
      #pragma unroll
      for(int off=1;off<16;off<<=1) rs[rg] += __shfl_xor(rs[rg], off, 64);
      lrun[rg] = lrun[rg]*alpha[rg] + rs[rg];
      oacc[0][rg] *= alpha[rg]; oacc[1][rg] *= alpha[rg];
    }
    // P: C-layout -> LDS -> A-layout; own-wave region only, lgkmcnt wait suffices (no barrier)
    #pragma unroll
    for(int n=0;n<8;n++)
      #pragma unroll
      for(int rg=0;rg<4;rg++)
        Ps[w*16*136 + (quad*4+rg)*136 + n*16 + l15] = f2b(s[n][rg]);
    #pragma unroll
    for(int kt2=0;kt2<4;kt2++){
      short8 ap = *(short8*)&Ps[w*16*136 + l15*136 + kt2*32 + quad*8];
      #pragma unroll
      for(int n2=0;n2<2;n2++)
        oacc[n2] = MFMA16(ap, *(short8*)&Vt[cur][(n2*16+l15)*136 + kt2*32 + quad*8], oacc[n2]);
    }
    if(kti<15){                             // commit next K/V to the other LDS buffer
      #pragma unroll
      for(int i=0;i<2;i++){
        int key = skey + 64*i;
        *(uint4*)&Ksh[cur^1][key*40 + sc4*8] = kreg[i];
        u16 tmp[8]; *(uint4*)tmp = vreg[i];
        #pragma unroll
        for(int j=0;j<8;j++) Vt[cur^1][(sc4*8+j)*136 + key] = tmp[j];
      }
    }
    __syncthreads();
  }
  float* op = opart + ((size_t)b << 11);          // 64 x 32 f32
  #pragma unroll
  for(int n2=0;n2<2;n2++)
    #pragma unroll
    for(int rg=0;rg<4;rg++)
      op[(w*16+quad*4+rg)*32 + n2*16 + l15] = oacc[n2][rg];
  if(l15 == 0){
    float* ml = mlpart + ((size_t)b << 7);        // [2][64]
    #pragma unroll
    for(int rg=0;rg<4;rg++){
      int r = w*16 + quad*4 + rg;
      ml[r] = sc*mrun[rg]; ml[64 + r] = lrun[rg]; // store m in scaled domain
    }
  }
}

// ---------------- attn-out proj: combine kt-halves during A staging, + bias + residual + LN ----
__global__ __launch_bounds__(256) void k_oprojln(const float* __restrict__ opart, const float* __restrict__ mlpart,
                                                 const float* __restrict__ W,
                                                 const float* __restrict__ bias, const float* __restrict__ resf,
                                                 const float* __restrict__ g, const float* __restrict__ bb,
                                                 float* __restrict__ outf, u16* __restrict__ outb){
  __shared__ u16 As[128*72], Bs[128*72];
  int mt = blockIdx.x;   // grid 32
  int t=threadIdx.x, w=t>>6, lane=t&63, l15=lane&15, quad=lane>>4;
  f32x4 acc[2][8];
  #pragma unroll
  for(int s=0;s<2;s++)
    #pragma unroll
    for(int n=0;n<8;n++) acc[s][n] = (f32x4){0.f,0.f,0.f,0.f};
  #pragma unroll
  for(int step=0; step<2; step++){
    int kb = step*64;
    __syncthreads();
    #pragma unroll
    for(int i=0;i<4;i++){
      int id = t + 256*i; int row = id>>3, c8 = id&7;
      // A: combined attention output for (grow, col..col+7)
      int col = kb + c8*8;
      int hh = col>>5, c0 = col&31;
      int grow = mt*128 + row;
      int hq = hh*64 + (grow>>6);
      int rr = grow & 63;
      const float* o0  = opart  + ((size_t)(hq*2)   << 11);
      const float* o1  = opart  + ((size_t)(hq*2+1) << 11);
      const float* ml0 = mlpart + ((size_t)(hq*2)   << 7);
      const float* ml1 = mlpart + ((size_t)(hq*2+1) << 7);
      float m0 = ml0[rr], l0 = ml0[64+rr], m1 = ml1[rr], l1 = ml1[64+rr];
      float m = fmaxf(m0, m1);
      float w0 = __expf(m0 - m), w1 = __expf(m1 - m);
      float inv = 1.f / (l0*w0 + l1*w1);
      float4 a0 = *(const float4*)&o0[rr*32 + c0];
      float4 a1 = *(const float4*)&o0[rr*32 + c0 + 4];
      float4 c0v = *(const float4*)&o1[rr*32 + c0];
      float4 c1v = *(const float4*)&o1[rr*32 + c0 + 4];
      ushort4 p0 = { f2b((a0.x*w0+c0v.x*w1)*inv), f2b((a0.y*w0+c0v.y*w1)*inv),
                     f2b((a0.z*w0+c0v.z*w1)*inv), f2b((a0.w*w0+c0v.w*w1)*inv) };
      ushort4 p1 = { f2b((a1.x*w0+c1v.x*w1)*inv), f2b((a1.y*w0+c1v.y*w1)*inv),
                     f2b((a1.z*w0+c1v.z*w1)*inv), f2b((a1.w*w0+c1v.w*w1)*inv) };
      *(ushort4*)&As[row*72 + c8*8]     = p0;
      *(ushort4*)&As[row*72 + c8*8 + 4] = p1;
      // B: Wo f32 -> bf16
      float4 f0 = *(const float4*)&W[(size_t)row*DIM + kb + c8*8];
      float4 f1 = *(const float4*)&W[(size_t)row*DIM + kb + c8*8 + 4];
      ushort4 q0 = { f2b(f0.x), f2b(f0.y), f2b(f0.z), f2b(f0.w) };
      ushort4 q1 = { f2b(f1.x), f2b(f1.y), f2b(f1.z), f2b(f1.w) };
      *(ushort4*)&Bs[row*72 + c8*8]     = q0;
      *(ushort4*)&Bs[row*72 + c8*8 + 4] = q1;
    }
    __syncthreads();
    #pragma unroll
    for(int ks=0; ks<2; ks++){
      short8 a[2], b[8];
      #pragma unroll
      for(int s=0;s<2;s++) a[s] = *(short8*)&As[(w*32+s*16+l15)*72 + (ks*4+quad)*8];
      #pragma unroll
      for(int n=0;n<8;n++)  b[n] = *(short8*)&Bs[(n*16+l15)*72 + (ks*4+quad)*8];
      #pragma unroll
      for(int s=0;s<2;s++)
        #pragma unroll
        for(int n=0;n<8;n++) acc[s][n] = MFMA16(a[s], b[n], acc[s][n]);
    }
  }
  #pragma unroll
  for(int s=0;s<2;s++)
    #pragma unroll
    for(int n=0;n<8;n++)
      #pragma unroll
      for(int rg=0;rg<4;rg++){
        int row = mt*128 + w*32 + s*16 + quad*4 + rg;
        int col = n*16 + l15;
        acc[s][n][rg] += bias[col] + resf[(size_t)row*DIM + col];
      }
  #pragma unroll
  for(int s=0;s<2;s++)
    #pragma unroll
    for(int rg=0;rg<4;rg++){
      float a=0.f, bsum=0.f;
      #pragma unroll
      for(int n=0;n<8;n++){ float x = acc[s][n][rg]; a += x; bsum += x*x; }
      #pragma unroll
      for(int off=1;off<16;off<<=1){ a += __shfl_xor(a, off, 64); bsum += __shfl_xor(bsum, off, 64); }
      float mean = a*(1.f/128.f);
      float var  = bsum*(1.f/128.f) - mean*mean;
      float rstd = rsqrtf(var + 1e-5f);
      #pragma unroll
      for(int n=0;n<8;n++){
        int row = mt*128 + w*32 + s*16 + quad*4 + rg;
        int col = n*16 + l15;
        float y = (acc[s][n][rg] - mean)*rstd*g[col] + bb[col];
        outf[(size_t)row*DIM + col] = y;
        outb[(size_t)row*DIM + col] = f2b(y);
      }
    }
}

// ---------------- C = A@W^T + bias + residual, then LayerNorm -> f32 + bf16 ----------------
__global__ __launch_bounds__(256) void k_projln(const u16* __restrict__ Ab, const float* __restrict__ W,
                                                const float* __restrict__ bias, const float* __restrict__ resf,
                                                const float* __restrict__ g, const float* __restrict__ bb,
                                                float* __restrict__ outf, u16* __restrict__ outb){
  __shared__ u16 As[128*72], Bs[128*72];
  int mt = blockIdx.x;   // grid 32
  f32x4 acc[2][8];
  gemm_k128_t<false,true>(Ab + (size_t)mt*128*DIM, DIM, W, DIM, As, Bs, acc);
  int t=threadIdx.x, w=t>>6, lane=t&63, l15=lane&15, quad=lane>>4;
  #pragma unroll
  for(int s=0;s<2;s++)
    #pragma unroll
    for(int n=0;n<8;n++)
      #pragma unroll
      for(int rg=0;rg<4;rg++){
        int row = mt*128 + w*32 + s*16 + quad*4 + rg;
        int col = n*16 + l15;
        acc[s][n][rg] += bias[col] + resf[(size_t)row*DIM + col];
      }
  #pragma unroll
  for(int s=0;s<2;s++)
    #pragma unroll
    for(int rg=0;rg<4;rg++){
      float a=0.f, bsum=0.f;
      #pragma unroll
      for(int n=0;n<8;n++){ float x = acc[s][n][rg]; a += x; bsum += x*x; }
      #pragma unroll
      for(int off=1;off<16;off<<=1){ a += __shfl_xor(a, off, 64); bsum += __shfl_xor(bsum, off, 64); }
      float mean = a*(1.f/128.f);
      float var  = bsum*(1.f/128.f) - mean*mean;
      float rstd = rsqrtf(var + 1e-5f);
      #pragma unroll
      for(int n=0;n<8;n++){
        int row = mt*128 + w*32 + s*16 + quad*4 + rg;
        int col = n*16 + l15;
        float y = (acc[s][n][rg] - mean)*rstd*g[col] + bb[col];
        outf[(size_t)row*DIM + col] = y;
        outb[(size_t)row*DIM + col] = f2b(y);
      }
    }
}

// ---------------- ff1 = gelu_tanh(x @ W1^T + b1) -> bf16 ----------------
__global__ __launch_bounds__(256) void k_ff1(const u16* __restrict__ Ab, const float* __restrict__ W,
                                             const float* __restrict__ bias, u16* __restrict__ outb){
  __shared__ u16 As[128*72], Bs[128*72];
  int mt = blockIdx.x;   // grid 32
  f32x4 acc[2][8];
  gemm_k128_t<false,true>(Ab + (size_t)mt*128*DIM, DIM, W, DIM, As, Bs, acc);
  int t=threadIdx.x, w=t>>6, lane=t&63, l15=lane&15, quad=lane>>4;
  #pragma unroll
  for(int s=0;s<2;s++)
    #pragma unroll
    for(int n=0;n<8;n++)
      #pragma unroll
      for(int rg=0;rg<4;rg++){
        int row = mt*128 + w*32 + s*16 + quad*4 + rg;
        int col = n*16 + l15;
        float v = acc[s][n][rg] + bias[col];
        float z = 0.7978845608028654f*(v + 0.044715f*v*v*v);
        float e = __expf(2.f*z);
        float th = 1.f - 2.f/(e + 1.f);     // tanh(z), overflow-safe
        outb[(size_t)row*DIM + col] = f2b(0.5f*v*(1.f + th));
      }
}

// ---------------- per-visit masked mean pooling (f32 out) ----------------
__global__ __launch_bounds__(256) void k_pool(const int* __restrict__ visits, const float* __restrict__ xf,
                                              float* __restrict__ out){
  int t = threadIdx.x;
  int vis = blockIdx.x*2 + (t>>7);
  int col = t & 127;
  float s = 0.f; int cnt = 0;
  #pragma unroll
  for(int j=0;j<MAXC;j++){
    int idx = visits[vis*MAXC + j];
    if(idx != 0){ s += xf[(size_t)idx*DIM + col]; cnt++; }
  }
  float r = (cnt > 0) ? s/(float)cnt : 0.f;
  out[(size_t)vis*DIM + col] = r;
}

extern "C" void kernel_launch(void* const* d_in, const int* in_sizes, int n_in,
                              void* d_out, int out_size, void* d_ws, size_t ws_size,
                              hipStream_t stream){
  (void)in_sizes; (void)n_in; (void)out_size; (void)ws_size;
  const int*   visits = (const int*)d_in[0];
  const float* xhyp  = (const float*)d_in[1];
  const float* kers  = (const float*)d_in[2];
  const float* projW = (const float*)d_in[3];
  const float* projb = (const float*)d_in[4];
  const float* Wqkv  = (const float*)d_in[5];
  const float* bqkv  = (const float*)d_in[6];
  const float* Wo    = (const float*)d_in[7];
  const float* bo    = (const float*)d_in[8];
  const float* W1    = (const float*)d_in[9];
  const float* b1    = (const float*)d_in[10];
  const float* W2    = (const float*)d_in[11];
  const float* b2    = (const float*)d_in[12];
  const float* g1    = (const float*)d_in[13];
  const float* be1   = (const float*)d_in[14];
  const float* g2    = (const float*)d_in[15];
  const float* be2   = (const float*)d_in[16];

  char* ws = (char*)d_ws;
  u16*   z0    = (u16*)(ws);                // 1 MB : Z0 bf16 [4096][128]
  u16*   gbuf  = (u16*)(ws + (1u<<20));     // 3 MB : G bf16 [128][3][4096]
  float* h0    = (float*)(ws + (4u<<20));   // 2 MB : H0 f32
  u16*   qkvb  = (u16*)(ws + (7u<<20));     // 3 MB
  float* ln1f  = (float*)(ws + (11u<<20));  // 2 MB
  u16*   ln1b  = (u16*)(ws + (13u<<20));    // 1 MB
  u16*   ffa   = (u16*)(ws + (14u<<20));    // 1 MB
  float* x1f   = (float*)(ws + (15u<<20));  // 2 MB
  u16*   x1b   = (u16*)(ws + (17u<<20));    // 1 MB
  float* x2f   = (float*)(ws + (18u<<20));  // 2 MB
  u16*   x2b   = (u16*)(ws + (20u<<20));    // 1 MB
  u16*   hpart = (u16*)(ws + (21u<<20));    // 16 MB : 512 x (128x128) bf16 partials
  float* opart = (float*)(ws + (53u<<20));  // 4 MB  : 512 x (64x32) f32
  float* mlprt = (float*)(ws + (57u<<20));  // 256 KB: 512 x [2][64] f32

  k_logmap<<<64,256,0,stream>>>(xhyp, z0);
  k_gproj<<<96,256,0,stream>>>(projW, z0, gbuf);
  k_diff<<<512,256,0,stream>>>(kers, gbuf, hpart);
  k_hreduce<<<512,256,0,stream>>>(hpart, projb, h0);

  const void* curA = (const void*)h0; bool af32 = true;
  const float* curf = h0;
  float* outfs[2] = {x1f, x2f}; u16* outbs[2] = {x1b, x2b};
  for(int l=0;l<2;l++){
    if(af32) k_qkv<true ><<<96,256,0,stream>>>(curA, Wqkv + (size_t)l*3*DIM*DIM, bqkv + (size_t)l*3*DIM, qkvb);
    else     k_qkv<false><<<96,256,0,stream>>>(curA, Wqkv + (size_t)l*3*DIM*DIM, bqkv + (size_t)l*3*DIM, qkvb);
    k_attn<<<512,256,0,stream>>>(qkvb, opart, mlprt);
    k_oprojln<<<32,256,0,stream>>>(opart, mlprt, Wo + (size_t)l*DIM*DIM, bo + (size_t)l*DIM, curf,
                                   g1 + (size_t)l*DIM, be1 + (size_t)l*DIM, ln1f, ln1b);
    k_ff1<<<32,256,0,stream>>>(ln1b, W1 + (size_t)l*DIM*DIM, b1 + (size_t)l*DIM, ffa);
    k_projln<<<32,256,0,stream>>>(ffa, W2 + (size_t)l*DIM*DIM, b2 + (size_t)l*DIM, ln1f,
                                  g2 + (size_t)l*DIM, be2 + (size_t)l*DIM, outfs[l], outbs[l]);
    curA = (const void*)outbs[l]; af32 = false; curf = outfs[l];
  }
  k_pool<<<4096,256,0,stream>>>(visits, curf, (float*)d_out);
}